// Round 8
// baseline (30.114 us; speedup 1.0000x reference)
//
#include <hip/hip_runtime.h>
#include <math.h>

#define DIM 1024
#define KK 7
#define DIL 2
#define BATCH 16384
#define NEG 0.01f
#define ROWS 8    // rows per block (trans-table amortization), grid = 2048 blocks
#define PF 4      // prefetch depth: rows in flight per wave (~4 KB) -> Little's law

typedef float floatx4 __attribute__((ext_vector_type(4)));

// ---------------------------------------------------------------------------
// Register-stream kernel, prefetch depth 4. 2048 blocks x 256 threads; block
// b owns rows [b*8, b*8+8); thread t owns features 4t..4t+3 for all its rows
// (per-feature transcendental table computed once per block, in registers).
// No LDS staging, no mid-kernel barrier: the read stream is kept continuously
// 3-4 rows deep per wave so the CU always has enough outstanding reads to
// saturate HBM (R7 post-mortem: barrier-phased loads oscillate and cap at
// ~55% of achievable BW).
// ---------------------------------------------------------------------------
__global__ __launch_bounds__(256, 4)   // cap VGPR at 128 -> 16 waves/CU
void cnn_flow_fused(const float* __restrict__ x,
                    const float* __restrict__ wgt,
                    const float* __restrict__ bias,
                    const float* __restrict__ lmbd,
                    float* __restrict__ out,
                    float* __restrict__ logdet) {
    const int t    = threadIdx.x;
    const int wv   = t >> 6;
    const int lane = t & 63;
    const int base = t << 2;                      // 4 features per thread
    const int row0 = blockIdx.x * ROWS;

    // weights + bias: wave-uniform scalar loads, L2-resident
    float w[KK];
#pragma unroll
    for (int k = 0; k < KK; ++k) w[k] = wgt[k];
    const float w0 = w[0];
    const float bs = bias[0];

    // per-feature tables, once per block (registers, reused for all ROWS rows)
    float sc[4], lp[4], ln[4];
    {
        float4 lm = *reinterpret_cast<const float4*>(lmbd + base);
        float lms[4] = {lm.x, lm.y, lm.z, lm.w};
        const float inv = (w0 != 0.0f) ? (-1.0f / w0) : 0.0f;
#pragma unroll
        for (int i = 0; i < 4; ++i) {
            float l  = lms[i];
            float sp = fmaxf(l, 0.0f) + log1pf(expf(-fabsf(l)));  // softplus
            float scale;
            if (w0 == 0.0f)      scale = l;
            else if (w0 > 0.0f)  scale = inv + sp;
            else                 scale = inv - sp;
            sc[i] = scale;
            lp[i] = logf(fabsf(fmaf(scale,       w0, 1.0f)));   // act_grad=1
            ln[i] = logf(fabsf(fmaf(NEG * scale, w0, 1.0f)));   // act_grad=NEG
        }
    }

    // conv window loader: 16 floats [base, base+16), right zero-pad past DIM.
    // 4 overlapping float4 loads; redundant ones are L1/L2 hits (HBM ~1x).
    auto load_window = [&](const float* __restrict__ xrow, float* xv) {
        if (base + 16 <= DIM) {
#pragma unroll
            for (int j = 0; j < 4; ++j) {
                float4 v = *reinterpret_cast<const float4*>(xrow + base + 4 * j);
                xv[4 * j + 0] = v.x; xv[4 * j + 1] = v.y;
                xv[4 * j + 2] = v.z; xv[4 * j + 3] = v.w;
            }
        } else {
#pragma unroll
            for (int j = 0; j < 16; ++j) {
                int idx = base + j;
                xv[j] = (idx < DIM) ? xrow[idx] : 0.0f;
            }
        }
    };

    __shared__ float red[ROWS][4];                // per-row wave partials

    // prime the pipeline: rows 0..PF-1 in flight
    float win[PF][16];
#pragma unroll
    for (int p = 0; p < PF; ++p)
        load_window(x + (size_t)(row0 + p) * DIM, win[p]);

#pragma unroll
    for (int r = 0; r < ROWS; ++r) {
        // consume buffer slot, then immediately refill it with row r+PF
        float xv[16];
#pragma unroll
        for (int j = 0; j < 16; ++j) xv[j] = win[r & (PF - 1)][j];
        if (r + PF < ROWS)
            load_window(x + (size_t)(row0 + r + PF) * DIM, win[r & (PF - 1)]);

        float ld_acc = 0.0f;
        float o[4];
#pragma unroll
        for (int i = 0; i < 4; ++i) {
            float conv = bs;
#pragma unroll
            for (int k = 0; k < KK; ++k)
                conv = fmaf(xv[i + DIL * k], w[k], conv);
            bool pos  = (conv >= 0.0f);
            float act = pos ? conv : NEG * conv;
            o[i]      = fmaf(act, sc[i], xv[i]);
            ld_acc   += pos ? lp[i] : ln[i];
        }
        floatx4 ov; ov.x = o[0]; ov.y = o[1]; ov.z = o[2]; ov.w = o[3];
        __builtin_nontemporal_store(ov,
            reinterpret_cast<floatx4*>(out + (size_t)(row0 + r) * DIM + base));

        // wave shuffle reduce (latency hidden, per R6 A/B); park per-wave partial
#pragma unroll
        for (int off = 32; off > 0; off >>= 1)
            ld_acc += __shfl_down(ld_acc, off, 64);
        if (lane == 0) red[r][wv] = ld_acc;
    }

    __syncthreads();                              // single barrier per block
    if (t < ROWS)
        logdet[row0 + t] = (red[t][0] + red[t][1]) + (red[t][2] + red[t][3]);
}

extern "C" void kernel_launch(void* const* d_in, const int* in_sizes, int n_in,
                              void* d_out, int out_size, void* d_ws, size_t ws_size,
                              hipStream_t stream) {
    const float* x    = (const float*)d_in[0];
    const float* wgt  = (const float*)d_in[1];
    const float* bias = (const float*)d_in[2];
    const float* lmbd = (const float*)d_in[3];
    float* out    = (float*)d_out;                    // (BATCH, DIM)
    float* logdet = out + (size_t)BATCH * DIM;        // (BATCH,)

    cnn_flow_fused<<<BATCH / ROWS, 256, 0, stream>>>(x, wgt, bias, lmbd, out, logdet);
}

// Round 9
// 29.495 us; speedup vs baseline: 1.0210x; 1.0210x over previous
//
#include <hip/hip_runtime.h>
#include <math.h>

#define DIM 1024
#define KK 7
#define DIL 2
#define BATCH 16384
#define NEG 0.01f
#define ROWS 8    // rows per block: amortizes trans table, grid = 2048 blocks

// ---------------------------------------------------------------------------
// A/B vs R6: ONLY change is plain float4 stores instead of
// __builtin_nontemporal_store (nt sets cache-bypass bits that may defeat L2
// write combining; every 28-30us plateau kernel used nt, while the 6.7 TB/s
// fill kernel and the 6.3 TB/s copy ceiling use plain stores).
// Everything else identical to R6: 2048 blocks x 256 threads, 8 rows/block,
// per-block register trans table, depth-1 prefetch, fire-and-forget LDS
// stash + end-of-block reduce for logdet.
// ---------------------------------------------------------------------------
__global__ __launch_bounds__(256)
void cnn_flow_fused(const float* __restrict__ x,
                    const float* __restrict__ wgt,
                    const float* __restrict__ bias,
                    const float* __restrict__ lmbd,
                    float* __restrict__ out,
                    float* __restrict__ logdet) {
    const int t    = threadIdx.x;
    const int base = t << 2;                      // 4 features per thread
    const int row0 = blockIdx.x * ROWS;

    // weights + bias: wave-uniform scalar loads, L2-resident
    float w[KK];
#pragma unroll
    for (int k = 0; k < KK; ++k) w[k] = wgt[k];
    const float w0 = w[0];
    const float bs = bias[0];

    // per-feature tables, once per block (registers, reused for all ROWS rows)
    float sc[4], lp[4], ln[4];
    {
        float4 lm = *reinterpret_cast<const float4*>(lmbd + base);
        float lms[4] = {lm.x, lm.y, lm.z, lm.w};
        const float inv = (w0 != 0.0f) ? (-1.0f / w0) : 0.0f;
#pragma unroll
        for (int i = 0; i < 4; ++i) {
            float l  = lms[i];
            float sp = fmaxf(l, 0.0f) + log1pf(expf(-fabsf(l)));  // softplus
            float scale;
            if (w0 == 0.0f)      scale = l;       // wave-uniform branch
            else if (w0 > 0.0f)  scale = inv + sp;
            else                 scale = inv - sp;
            sc[i] = scale;
            lp[i] = logf(fabsf(fmaf(scale,       w0, 1.0f)));   // act_grad=1
            ln[i] = logf(fabsf(fmaf(NEG * scale, w0, 1.0f)));   // act_grad=NEG
        }
    }

    // conv window loader: 16 floats [base, base+16), right zero-pad past DIM.
    // 4 overlapping float4 loads; redundant ones are L1 hits (HBM ~1x).
    auto load_window = [&](const float* __restrict__ xrow, float* xv) {
        if (base + 16 <= DIM) {
#pragma unroll
            for (int j = 0; j < 4; ++j) {
                float4 v = *reinterpret_cast<const float4*>(xrow + base + 4 * j);
                xv[4 * j + 0] = v.x; xv[4 * j + 1] = v.y;
                xv[4 * j + 2] = v.z; xv[4 * j + 3] = v.w;
            }
        } else {
#pragma unroll
            for (int j = 0; j < 16; ++j) {
                int idx = base + j;
                xv[j] = (idx < DIM) ? xrow[idx] : 0.0f;
            }
        }
    };

    __shared__ float red[ROWS][256];              // per-thread partials, 8 KB

    float xv[16];
    load_window(x + (size_t)row0 * DIM, xv);

#pragma unroll
    for (int r = 0; r < ROWS; ++r) {
        // 1-ahead prefetch; full unroll -> xn is register-renamed
        float xn[16];
        if (r + 1 < ROWS)
            load_window(x + (size_t)(row0 + r + 1) * DIM, xn);

        float ld_acc = 0.0f;
        float o[4];
#pragma unroll
        for (int i = 0; i < 4; ++i) {
            float conv = bs;
#pragma unroll
            for (int k = 0; k < KK; ++k)
                conv = fmaf(xv[i + DIL * k], w[k], conv);
            bool pos  = (conv >= 0.0f);
            float act = pos ? conv : NEG * conv;
            o[i]      = fmaf(act, sc[i], xv[i]);
            ld_acc   += pos ? lp[i] : ln[i];
        }
        *reinterpret_cast<float4*>(out + (size_t)(row0 + r) * DIM + base) =
            make_float4(o[0], o[1], o[2], o[3]);   // plain store (the A/B)

        // fire-and-forget stash (conflict-free: thread t -> word t)
        red[r][t] = ld_acc;

        if (r + 1 < ROWS) {
#pragma unroll
            for (int j = 0; j < 16; ++j) xv[j] = xn[j];
        }
    }

    __syncthreads();                              // single barrier per block

    // end-of-block reduce: wave wv handles rows {wv, wv+4}
    const int wv   = t >> 6;
    const int lane = t & 63;
#pragma unroll
    for (int rr = 0; rr < 2; ++rr) {
        const int r = wv + 4 * rr;
        float v = red[r][lane] + red[r][lane + 64] +
                  red[r][lane + 128] + red[r][lane + 192];
#pragma unroll
        for (int off = 32; off > 0; off >>= 1)
            v += __shfl_down(v, off, 64);
        if (lane == 0) logdet[row0 + r] = v;
    }
}

extern "C" void kernel_launch(void* const* d_in, const int* in_sizes, int n_in,
                              void* d_out, int out_size, void* d_ws, size_t ws_size,
                              hipStream_t stream) {
    const float* x    = (const float*)d_in[0];
    const float* wgt  = (const float*)d_in[1];
    const float* bias = (const float*)d_in[2];
    const float* lmbd = (const float*)d_in[3];
    float* out    = (float*)d_out;                    // (BATCH, DIM)
    float* logdet = out + (size_t)BATCH * DIM;        // (BATCH,)

    cnn_flow_fused<<<BATCH / ROWS, 256, 0, stream>>>(x, wgt, bias, lmbd, out, logdet);
}

// Round 10
// 26.830 us; speedup vs baseline: 1.1224x; 1.0993x over previous
//
#include <hip/hip_runtime.h>
#include <math.h>

#define DIM 1024
#define KK 7
#define DIL 2
#define BATCH 16384
#define NEG 0.01f
#define ROWS 8      // rows per block, grid = 2048
#define RST 1040    // LDS row stride in floats: 1024 + 16 zero-pad
#define NBUF 3      // triple buffer of 2-row tiles (issue-ahead 1, laggard-safe)

// Direct global->LDS DMA, 16B/lane, no destination VGPR -> compiler cannot
// sink it; completion tracked by vmcnt.
__device__ __forceinline__ void gload_lds16(const float* g, float* l) {
    __builtin_amdgcn_global_load_lds(
        (const __attribute__((address_space(1))) void*)g,
        (__attribute__((address_space(3))) void*)l, 16, 0, 0);
}

// ---------------------------------------------------------------------------
// Pipelined LDS staging (T3/T4 minimum form): per iter k (2 rows):
//   issue gload_lds for tile k+1 -> buf (k+1)%3      (2 VMEM, fire-and-forget)
//   s_waitcnt vmcnt(counted)                          (tile k complete; tile
//                                                      k+1 + old stores stay
//                                                      IN FLIGHT across barrier)
//   raw s_barrier                                     (cross-wave halo visible;
//                                                      no vmcnt(0) drain!)
//   compute rows 2k,2k+1 from buf k%3 (ds_read_b128 windows, 28-FMA conv,
//   leaky-relu/scale/skip, plain float4 store, wave shuffle-reduce logdet)
// Buffer safety: issue target (k+1)%3, current read k%3, laggard read (k-1)%3
// are pairwise distinct mod 3. Memory system sees continuous read issue ->
// no load/compute phase oscillation (R7's failure mode).
// ---------------------------------------------------------------------------
__global__ __launch_bounds__(256)
void cnn_flow_fused(const float* __restrict__ x,
                    const float* __restrict__ wgt,
                    const float* __restrict__ bias,
                    const float* __restrict__ lmbd,
                    float* __restrict__ out,
                    float* __restrict__ logdet) {
    const int t    = threadIdx.x;
    const int wv   = t >> 6;
    const int lane = t & 63;
    const int base = t << 2;                  // 4 features per thread
    const int row0 = blockIdx.x * ROWS;

    __shared__ float sx[NBUF * 2 * RST];      // 24.96 KB staging
    __shared__ float red[ROWS][4];            // per-row wave partials

    // wave wv stages segment [wv*256, wv*256+256) floats of each row
    const float* gseg = x + (size_t)row0 * DIM + (wv << 8) + (lane << 2);
    float*       lseg = sx + (wv << 8) + (lane << 2);

    // zero the 16-float pad of all 6 LDS rows (gload never touches pads)
    if (t < NBUF * 2 * 16)
        sx[(t >> 4) * RST + DIM + (t & 15)] = 0.0f;

    // prologue: issue tile 0 (rows 0,1 -> buf 0)
    gload_lds16(gseg + 0 * DIM, lseg + 0 * RST);
    gload_lds16(gseg + 1 * DIM, lseg + 1 * RST);

    // scalar params + per-feature tables computed while tile-0 loads fly
    float w[KK];
#pragma unroll
    for (int k = 0; k < KK; ++k) w[k] = wgt[k];
    const float w0 = w[0];
    const float bs = bias[0];

    float sc[4], lp[4], ln[4];
    {
        float4 lm = *reinterpret_cast<const float4*>(lmbd + base);
        float lms[4] = {lm.x, lm.y, lm.z, lm.w};
        const float inv = (w0 != 0.0f) ? (-1.0f / w0) : 0.0f;
#pragma unroll
        for (int i = 0; i < 4; ++i) {
            float l  = lms[i];
            float sp = fmaxf(l, 0.0f) + log1pf(expf(-fabsf(l)));  // softplus
            float scale;
            if (w0 == 0.0f)      scale = l;
            else if (w0 > 0.0f)  scale = inv + sp;
            else                 scale = inv - sp;
            sc[i] = scale;
            lp[i] = logf(fabsf(fmaf(scale,       w0, 1.0f)));   // act_grad=1
            ln[i] = logf(fabsf(fmaf(NEG * scale, w0, 1.0f)));   // act_grad=NEG
        }
    }

#pragma unroll
    for (int k = 0; k < ROWS / 2; ++k) {
        // issue next tile into buf (k+1)%3 — before consuming tile k
        if (k < ROWS / 2 - 1) {
            float* lb = sx + ((k + 1) % NBUF) * 2 * RST + (wv << 8) + (lane << 2);
            gload_lds16(gseg + (2 * k + 2) * DIM, lb);
            gload_lds16(gseg + (2 * k + 3) * DIM, lb + RST);
        }
        // counted wait: retire tile k's 2 loads (oldest); keep the rest flying.
        // vmcnt budget at this point: [tile k: 2][stores k-1: 2][tile k+1: 2]
        if (k == 0)
            asm volatile("s_waitcnt vmcnt(2) lgkmcnt(0)" ::: "memory");
        else if (k < ROWS / 2 - 1)
            asm volatile("s_waitcnt vmcnt(4)" ::: "memory");
        else
            asm volatile("s_waitcnt vmcnt(2)" ::: "memory");
        __builtin_amdgcn_s_barrier();     // raw: no vmcnt(0) drain

        const float* buf = sx + (k % NBUF) * 2 * RST;
#pragma unroll
        for (int rr = 0; rr < 2; ++rr) {
            const int r = 2 * k + rr;
            const float* srow = buf + rr * RST + base;
            float xv[16];
#pragma unroll
            for (int j = 0; j < 4; ++j) {     // 4x ds_read_b128, 2-way alias
                float4 v = *reinterpret_cast<const float4*>(srow + 4 * j);
                xv[4 * j + 0] = v.x; xv[4 * j + 1] = v.y;
                xv[4 * j + 2] = v.z; xv[4 * j + 3] = v.w;
            }

            float ld_acc = 0.0f;
            float o[4];
#pragma unroll
            for (int i = 0; i < 4; ++i) {
                float conv = bs;
#pragma unroll
                for (int kk = 0; kk < KK; ++kk)
                    conv = fmaf(xv[i + DIL * kk], w[kk], conv);
                bool pos  = (conv >= 0.0f);
                float act = pos ? conv : NEG * conv;
                o[i]      = fmaf(act, sc[i], xv[i]);
                ld_acc   += pos ? lp[i] : ln[i];
            }
            *reinterpret_cast<float4*>(out + (size_t)(row0 + r) * DIM + base) =
                make_float4(o[0], o[1], o[2], o[3]);

            // wave shuffle reduce (hidden, per R6 A/B); park per-wave partial
#pragma unroll
            for (int off = 32; off > 0; off >>= 1)
                ld_acc += __shfl_down(ld_acc, off, 64);
            if (lane == 0) red[r][wv] = ld_acc;
        }
    }

    __syncthreads();                          // kernel end: full drain is fine
    if (t < ROWS)
        logdet[row0 + t] = (red[t][0] + red[t][1]) + (red[t][2] + red[t][3]);
}

extern "C" void kernel_launch(void* const* d_in, const int* in_sizes, int n_in,
                              void* d_out, int out_size, void* d_ws, size_t ws_size,
                              hipStream_t stream) {
    const float* x    = (const float*)d_in[0];
    const float* wgt  = (const float*)d_in[1];
    const float* bias = (const float*)d_in[2];
    const float* lmbd = (const float*)d_in[3];
    float* out    = (float*)d_out;                    // (BATCH, DIM)
    float* logdet = out + (size_t)BATCH * DIM;        // (BATCH,)

    cnn_flow_fused<<<BATCH / ROWS, 256, 0, stream>>>(x, wgt, bias, lmbd, out, logdet);
}

// Round 11
// 26.181 us; speedup vs baseline: 1.1502x; 1.0248x over previous
//
#include <hip/hip_runtime.h>
#include <math.h>

#define DIM 1024
#define KK 7
#define DIL 2
#define BATCH 16384
#define NEG 0.01f
#define ROWS 8      // rows per block, grid = 2048 (= 8 blocks/CU exactly, no tail)
#define NBUF 3      // per-wave row slots (depth-2 prefetch + current)
#define DEPTH 2     // rows issued ahead
#define SLOT 320    // floats per slot: 256 main + 64 halo (windows read [0,268))

// Direct global->LDS DMA; no destination VGPR -> un-sinkable; vmcnt-tracked.
__device__ __forceinline__ void gload_lds16(const float* g, float* l) {
    __builtin_amdgcn_global_load_lds(
        (const __attribute__((address_space(1))) void*)g,
        (__attribute__((address_space(3))) void*)l, 16, 0, 0);
}
__device__ __forceinline__ void gload_lds4(const float* g, float* l) {
    __builtin_amdgcn_global_load_lds(
        (const __attribute__((address_space(1))) void*)g,
        (__attribute__((address_space(3))) void*)l, 4, 0, 0);
}

// ---------------------------------------------------------------------------
// Barrier-free wave pipelines. Each wave stages its own 256-float segment +
// 64-float halo per row into its private LDS slots, so window reads never
// cross waves -> no s_barrier in the hot loop; counted per-wave vmcnt only.
// Per iter r: [issue row r+2 loads][s_waitcnt vmcnt(N)][4x ds_read_b128 ->
// 28-FMA conv -> leaky-relu/scale/skip -> float4 store][shuffle logdet].
// vmcnt schedule from exact position counting (2 loads + 1 store per iter):
// {4,5,6,6,6,6,4,2}. Wave 3's halo is past DIM: dummy-dest load keeps the
// count symmetric; its halo LDS (zero-pad) is written once, never gloaded.
// ---------------------------------------------------------------------------
__global__ __launch_bounds__(256)
void cnn_flow_fused(const float* __restrict__ x,
                    const float* __restrict__ wgt,
                    const float* __restrict__ bias,
                    const float* __restrict__ lmbd,
                    float* __restrict__ out,
                    float* __restrict__ logdet) {
    const int t    = threadIdx.x;
    const int wv   = t >> 6;
    const int lane = t & 63;
    const int base = t << 2;                  // global feature = wv*256+lane*4
    const int row0 = blockIdx.x * ROWS;

    __shared__ float sx[4 * NBUF * SLOT];     // 15360 B staging
    __shared__ float red[ROWS][4];            // per-row wave partials
    __shared__ float dummy[64];               // sink for wave 3's halo loads

    // wave 3: zero the halo region of its own slots once (never gload-written)
    if (wv == 3) {
#pragma unroll
        for (int s = 0; s < NBUF; ++s)
            sx[(3 * NBUF + s) * SLOT + 256 + lane] = 0.0f;
    }

    const float* growbase = x + (size_t)row0 * DIM;
    const float* gmain = growbase + (wv << 8) + (lane << 2);          // 16B/lane
    const float* ghalo = growbase + ((wv < 3) ? (wv << 8) + 256 : 0) + lane; // 4B/lane

    auto issue_row = [&](int r) {
        float* slot = sx + (wv * NBUF + (r % NBUF)) * SLOT;
        gload_lds16(gmain + r * DIM, slot + (lane << 2));
        gload_lds4(ghalo + r * DIM, ((wv < 3) ? slot + 256 : dummy) + lane);
    };

    // prologue: rows 0,1 in flight
    issue_row(0);
    issue_row(1);

    // scalar params + per-feature tables: computed while prologue loads fly
    float w[KK];
#pragma unroll
    for (int k = 0; k < KK; ++k) w[k] = wgt[k];
    const float w0 = w[0];
    const float bs = bias[0];

    float sc[4], lp[4], ln[4];
    {
        float4 lm = *reinterpret_cast<const float4*>(lmbd + base);
        float lms[4] = {lm.x, lm.y, lm.z, lm.w};
        const float inv = (w0 != 0.0f) ? (-1.0f / w0) : 0.0f;
#pragma unroll
        for (int i = 0; i < 4; ++i) {
            float l  = lms[i];
            float sp = fmaxf(l, 0.0f) + log1pf(expf(-fabsf(l)));  // softplus
            float scale;
            if (w0 == 0.0f)      scale = l;
            else if (w0 > 0.0f)  scale = inv + sp;
            else                 scale = inv - sp;
            sc[i] = scale;
            lp[i] = logf(fabsf(fmaf(scale,       w0, 1.0f)));   // act_grad=1
            ln[i] = logf(fabsf(fmaf(NEG * scale, w0, 1.0f)));   // act_grad=NEG
        }
    }

#pragma unroll
    for (int r = 0; r < ROWS; ++r) {
        if (r + DEPTH < ROWS) issue_row(r + DEPTH);

        // counted per-wave wait: row r's 2 loads retired, newer loads + stores
        // stay in flight. Position-derived: {4,5,6,6,6,6,4,2}.
        if      (r == 0) asm volatile("s_waitcnt vmcnt(4)" ::: "memory");
        else if (r == 1) asm volatile("s_waitcnt vmcnt(5)" ::: "memory");
        else if (r == 6) asm volatile("s_waitcnt vmcnt(4)" ::: "memory");
        else if (r == 7) asm volatile("s_waitcnt vmcnt(2)" ::: "memory");
        else             asm volatile("s_waitcnt vmcnt(6)" ::: "memory");

        const float* srow = sx + (wv * NBUF + (r % NBUF)) * SLOT + (lane << 2);
        float xv[16];
#pragma unroll
        for (int j = 0; j < 4; ++j) {         // 4x ds_read_b128, wave-private
            float4 v = *reinterpret_cast<const float4*>(srow + 4 * j);
            xv[4 * j + 0] = v.x; xv[4 * j + 1] = v.y;
            xv[4 * j + 2] = v.z; xv[4 * j + 3] = v.w;
        }

        float ld_acc = 0.0f;
        float o[4];
#pragma unroll
        for (int i = 0; i < 4; ++i) {
            float conv = bs;
#pragma unroll
            for (int kk = 0; kk < KK; ++kk)
                conv = fmaf(xv[i + DIL * kk], w[kk], conv);
            bool pos  = (conv >= 0.0f);
            float act = pos ? conv : NEG * conv;
            o[i]      = fmaf(act, sc[i], xv[i]);
            ld_acc   += pos ? lp[i] : ln[i];
        }
        *reinterpret_cast<float4*>(out + (size_t)(row0 + r) * DIM + base) =
            make_float4(o[0], o[1], o[2], o[3]);

        // wave shuffle reduce (hidden); park per-wave partial, fire-and-forget
#pragma unroll
        for (int off = 32; off > 0; off >>= 1)
            ld_acc += __shfl_down(ld_acc, off, 64);
        if (lane == 0) red[r][wv] = ld_acc;
    }

    __syncthreads();                          // only barrier in the kernel
    if (t < ROWS)
        logdet[row0 + t] = (red[t][0] + red[t][1]) + (red[t][2] + red[t][3]);
}

extern "C" void kernel_launch(void* const* d_in, const int* in_sizes, int n_in,
                              void* d_out, int out_size, void* d_ws, size_t ws_size,
                              hipStream_t stream) {
    const float* x    = (const float*)d_in[0];
    const float* wgt  = (const float*)d_in[1];
    const float* bias = (const float*)d_in[2];
    const float* lmbd = (const float*)d_in[3];
    float* out    = (float*)d_out;                    // (BATCH, DIM)
    float* logdet = out + (size_t)BATCH * DIM;        // (BATCH,)

    cnn_flow_fused<<<BATCH / ROWS, 256, 0, stream>>>(x, wgt, bias, lmbd, out, logdet);
}